// Round 4
// baseline (494.514 us; speedup 1.0000x reference)
//
#include <hip/hip_runtime.h>
#include <math.h>

#define FIN 128
#define HID 16
#define NC 8
#define NPART 8
#define CH_PER_TH 16

// ---------------------------------------------------------------------------
// dtype probe: int64 vs int32 edge_index (device-side, uniform branch later)
// ---------------------------------------------------------------------------
__global__ void detect64_kernel(const void* __restrict__ ei, int E, int N,
                                int* __restrict__ flag) {
    if (blockIdx.x == 0 && threadIdx.x == 0) {
        const long long* p = (const long long*)ei;
        int ok = 1;
        for (int i = 0; i < 16; ++i) {
            long long v = p[i];
            if (v < 0 || v >= (long long)N) { ok = 0; break; }
        }
        *flag = ok;
    }
}

__device__ __forceinline__ int edge_at(const void* __restrict__ ei, long long pos, int is64) {
    return is64 ? (int)((const long long*)ei)[pos] : ((const int*)ei)[pos];
}

// A0: per-partition edge counts (LDS-reduced, 8 global atomics per block)
__global__ void countA0_kernel(const void* __restrict__ ei, int E, int N,
                               const int* __restrict__ flag, int* __restrict__ pcount) {
    __shared__ int cnt[NPART];
    const int is64 = *flag;
    const int PS = (N + NPART - 1) / NPART;
    const int t = threadIdx.x;
    if (t < NPART) cnt[t] = 0;
    __syncthreads();
    for (long long e = (long long)blockIdx.x * blockDim.x + t; e < E;
         e += (long long)gridDim.x * blockDim.x) {
        int d = edge_at(ei, (long long)E + e, is64);
        atomicAdd(&cnt[d / PS], 1);
    }
    __syncthreads();
    if (t < NPART) atomicAdd(&pcount[t], cnt[t]);
}

// exclusive scan of the 8 partition counts -> pstart, pcur
__global__ void setbase_kernel(const int* __restrict__ pcount,
                               int* __restrict__ pstart, int* __restrict__ pcur) {
    if (blockIdx.x == 0 && threadIdx.x == 0) {
        int run = 0;
        for (int b = 0; b < NPART; ++b) {
            pstart[b] = run; pcur[b] = run; run += pcount[b];
        }
    }
}

// A: coarse counting sort of edges into 8 dst-partitions (SoA src/dst).
// Per (block,bucket) runs are contiguous & block-exclusive -> full-line,
// single-eviction writes. Register arrays statically indexed.
__global__ __launch_bounds__(256) void passA_kernel(
        const void* __restrict__ ei, int E, int N, const int* __restrict__ flag,
        int* __restrict__ pcur, int* __restrict__ srcbuf, int* __restrict__ dstbuf) {
    const int is64 = *flag;
    const int PS = (N + NPART - 1) / NPART;
    __shared__ int cnt[NPART], sbase[NPART], lcur[NPART];
    const int t = threadIdx.x;
    const int CH = 256 * CH_PER_TH;
    for (long long c0 = (long long)blockIdx.x * CH; c0 < E;
         c0 += (long long)gridDim.x * CH) {
        if (t < NPART) { cnt[t] = 0; lcur[t] = 0; }
        __syncthreads();
        int sv[CH_PER_TH], dv[CH_PER_TH], bv[CH_PER_TH];
#pragma unroll
        for (int i = 0; i < CH_PER_TH; ++i) {
            long long e = c0 + t + i * 256;
            bv[i] = -1;
            if (e < E) {
                int s = edge_at(ei, e, is64);
                int d = edge_at(ei, (long long)E + e, is64);
                int b = d / PS;
                sv[i] = s; dv[i] = d; bv[i] = b;
                atomicAdd(&cnt[b], 1);
            }
        }
        __syncthreads();
        if (t < NPART) sbase[t] = atomicAdd(&pcur[t], cnt[t]);
        __syncthreads();
#pragma unroll
        for (int i = 0; i < CH_PER_TH; ++i) {
            if (bv[i] >= 0) {
                int pos = sbase[bv[i]] + atomicAdd(&lcur[bv[i]], 1);
                srcbuf[pos] = sv[i];
                dstbuf[pos] = dv[i];
            }
        }
        __syncthreads();
    }
}

// B: partition-pinned node histogram; counts slice (50KB) is L2-local,
// streams only the partition's 1.6MB dst slice -> no thrash.
__global__ void passB_hist_kernel(const int* __restrict__ dstbuf,
                                  const int* __restrict__ pstart,
                                  const int* __restrict__ pcount,
                                  int* __restrict__ counts) {
    const int part = blockIdx.x & (NPART - 1);
    const int lo = pstart[part], cnt = pcount[part];
    const int stride = (gridDim.x >> 3) * blockDim.x;
    for (int i = (blockIdx.x >> 3) * blockDim.x + threadIdx.x; i < cnt; i += stride)
        atomicAdd(&counts[dstbuf[lo + i]], 1);
}

// exclusive scan, stage A: 1024 elements/block (256 thr x 4), block totals out
__global__ void scanA_kernel(const int* __restrict__ counts, int* __restrict__ off,
                             int* __restrict__ bsum, int N) {
    __shared__ int s[256];
    int b = blockIdx.x, t = threadIdx.x;
    int base = b * 1024 + t * 4;
    int v[4], tot = 0;
#pragma unroll
    for (int i = 0; i < 4; ++i) {
        int idx = base + i;
        v[i] = (idx < N) ? counts[idx] : 0;
        tot += v[i];
    }
    s[t] = tot;
    __syncthreads();
    for (int d = 1; d < 256; d <<= 1) {
        int add = (t >= d) ? s[t - d] : 0;
        __syncthreads();
        s[t] += add;
        __syncthreads();
    }
    if (t == 255) bsum[b] = s[255];
    int run = (t > 0) ? s[t - 1] : 0;
#pragma unroll
    for (int i = 0; i < 4; ++i) {
        int idx = base + i;
        if (idx < N) off[idx] = run;
        run += v[i];
    }
}

__global__ void scanB_kernel(int* __restrict__ bsum, int nb) {
    if (threadIdx.x == 0 && blockIdx.x == 0) {
        int run = 0;
        for (int i = 0; i < nb; ++i) { int v = bsum[i]; bsum[i] = run; run += v; }
    }
}

__global__ void scanC_kernel(int* __restrict__ off, const int* __restrict__ bsum, int N) {
    int i = blockIdx.x * blockDim.x + threadIdx.x;
    if (i < N) off[i] += bsum[i >> 10];
}

// dinv[n] = rsqrt(counts[n] + 1)   (self loop adds 1)
__global__ void dinv_kernel(const int* __restrict__ counts, float* __restrict__ dinv, int N) {
    int n = blockIdx.x * blockDim.x + threadIdx.x;
    if (n < N) dinv[n] = rsqrtf((float)(counts[n] + 1));
}

// C: partition-pinned CSR scatter; reads the partition's 3.2MB (src,dst)
// slice, dirty set = off slice (50KB) + csr slice (1.6MB) -> fits L2,
// each line evicts ~once. off[d] advances to its end pointer.
__global__ void passC_scatter_kernel(const int* __restrict__ srcbuf,
                                     const int* __restrict__ dstbuf,
                                     const int* __restrict__ pstart,
                                     const int* __restrict__ pcount,
                                     int* __restrict__ off, int* __restrict__ csr_src) {
    const int part = blockIdx.x & (NPART - 1);
    const int lo = pstart[part], cnt = pcount[part];
    const int stride = (gridDim.x >> 3) * blockDim.x;
    for (int i = (blockIdx.x >> 3) * blockDim.x + threadIdx.x; i < cnt; i += stride) {
        int d = dstbuf[lo + i];
        int s = srcbuf[lo + i];
        int pos = atomicAdd(&off[d], 1);
        csr_src[pos] = s;
    }
}

// g1[n][k] = (sum_f x[n][f] * W1[f][k]) * dinv[n]
__global__ void transform1_kernel(const float* __restrict__ x,
                                  const float* __restrict__ W1,
                                  const float* __restrict__ dinv,
                                  float* __restrict__ g1, int N) {
    __shared__ float xs[16][FIN + 4];
    __shared__ float w[FIN][HID];
    const int t = threadIdx.x;
    for (int i = t; i < FIN * HID; i += 256) w[i / HID][i % HID] = W1[i];

    const float4* x4 = (const float4*)x;
    for (int rb = blockIdx.x * 16; rb < N; rb += gridDim.x * 16) {
        __syncthreads();
        for (int i = t; i < 16 * FIN / 4; i += 256) {
            int r = i >> 5, f4 = i & 31;
            int row = rb + r;
            float4 v = (row < N) ? x4[(size_t)row * (FIN / 4) + f4]
                                 : make_float4(0.f, 0.f, 0.f, 0.f);
            *((float4*)&xs[r][f4 * 4]) = v;
        }
        __syncthreads();
        int r = t >> 4, k = t & 15;
        int row = rb + r;
        if (row < N) {
            float s = 0.f;
#pragma unroll
            for (int f = 0; f < FIN; ++f) s += xs[r][f] * w[f][k];
            g1[(size_t)row * HID + k] = s * dinv[row];
        }
    }
}

// wave per node: 16 feature lanes x 4 edge-ways; fused ReLU finalize
__global__ void agg1_kernel(const int* __restrict__ off, const int* __restrict__ csr_src,
                            const float* __restrict__ g1, const float* __restrict__ dinv,
                            const float* __restrict__ b1, float* __restrict__ h, int N) {
    int wid = threadIdx.x >> 6;
    int lane = threadIdx.x & 63;
    int k = lane & 15, j = lane >> 4;                 // j in 0..3
    int wavesTotal = gridDim.x * (blockDim.x >> 6);
    for (int n = blockIdx.x * (blockDim.x >> 6) + wid; n < N; n += wavesTotal) {
        int start = (n == 0) ? 0 : off[n - 1];        // off[] holds END after scatter
        int end = off[n];
        float sum = 0.f;
        for (int e = start + j; e < end; e += 4)
            sum += g1[(size_t)csr_src[e] * HID + k];
        sum += __shfl_xor(sum, 16, 64);
        sum += __shfl_xor(sum, 32, 64);
        if (lane < 16) {
            float v = dinv[n] * (sum + g1[(size_t)n * HID + k]) + b1[k];
            h[(size_t)n * HID + k] = fmaxf(v, 0.f);
        }
    }
}

// g2[n][c] = (sum_k h[n][k] * W2[k][c]) * dinv[n]
__global__ void transform2_kernel(const float* __restrict__ h,
                                  const float* __restrict__ W2,
                                  const float* __restrict__ dinv,
                                  float* __restrict__ g2, int N) {
    int total = N * NC;
    for (int idx = blockIdx.x * blockDim.x + threadIdx.x; idx < total;
         idx += gridDim.x * blockDim.x) {
        int n = idx >> 3, c = idx & 7;
        float s = 0.f;
#pragma unroll
        for (int k = 0; k < HID; ++k) s += h[n * HID + k] * W2[k * NC + c];
        g2[idx] = s * dinv[n];
    }
}

// wave per node: 8 feature lanes x 8 edge-ways; fused log_softmax
__global__ void agg2_kernel(const int* __restrict__ off, const int* __restrict__ csr_src,
                            const float* __restrict__ g2, const float* __restrict__ dinv,
                            const float* __restrict__ b2, float* __restrict__ out, int N) {
    int wid = threadIdx.x >> 6;
    int lane = threadIdx.x & 63;
    int k = lane & 7, j = lane >> 3;                  // j in 0..7
    int wavesTotal = gridDim.x * (blockDim.x >> 6);
    for (int n = blockIdx.x * (blockDim.x >> 6) + wid; n < N; n += wavesTotal) {
        int start = (n == 0) ? 0 : off[n - 1];
        int end = off[n];
        float sum = 0.f;
        for (int e = start + j; e < end; e += 8)
            sum += g2[(size_t)csr_src[e] * NC + k];
        sum += __shfl_xor(sum, 8, 64);
        sum += __shfl_xor(sum, 16, 64);
        sum += __shfl_xor(sum, 32, 64);
        float logit = dinv[n] * (sum + g2[(size_t)n * NC + k]) + b2[k];
        float m = logit;
        m = fmaxf(m, __shfl_xor(m, 1, 64));
        m = fmaxf(m, __shfl_xor(m, 2, 64));
        m = fmaxf(m, __shfl_xor(m, 4, 64));
        float ex = __expf(logit - m);
        float s = ex;
        s += __shfl_xor(s, 1, 64);
        s += __shfl_xor(s, 2, 64);
        s += __shfl_xor(s, 4, 64);
        float lse = m + __logf(s);
        if (lane < 8) out[(size_t)n * NC + k] = logit - lse;
    }
}

extern "C" void kernel_launch(void* const* d_in, const int* in_sizes, int n_in,
                              void* d_out, int out_size, void* d_ws, size_t ws_size,
                              hipStream_t stream) {
    const float* x  = (const float*)d_in[0];
    const void*  ei = d_in[1];
    const float* W1 = (const float*)d_in[2];
    const float* b1 = (const float*)d_in[3];
    const float* W2 = (const float*)d_in[4];
    const float* b2 = (const float*)d_in[5];

    const int N = in_sizes[0] / FIN;
    const int E = in_sizes[1] / 2;
    const int NB = (N + 1023) / 1024;

    char* p = (char*)d_ws;
    int*   counts  = (int*)p;            p += (size_t)N * 4;
    int*   off     = (int*)p;            p += (size_t)N * 4;
    int*   bsum    = (int*)p;            p += (size_t)((NB + 63) & ~63) * 4;
    int*   csr_src = (int*)p;            p += (size_t)E * 4;
    float* dinv    = (float*)p;          p += (size_t)N * 4;
    int*   srcbuf  = (int*)p;            p += (size_t)E * 4;   // reused: g1
    int*   dstbuf  = (int*)p;            p += (size_t)E * 4;   // reused: h, g2
    int*   pcount  = (int*)p;            p += NPART * 4;
    int*   pstart  = (int*)p;            p += NPART * 4;
    int*   pcur    = (int*)p;            p += NPART * 4;
    int*   flag    = (int*)p;

    // aliases (consumed edge buffers reused as activation storage)
    float* g1 = (float*)srcbuf;                 // N*HID <= E floats
    float* h  = (float*)dstbuf;                 // N*HID
    float* g2 = (float*)dstbuf + (size_t)N * HID;  // N*NC (fits: HID+NC <= E/N*4)

    hipMemsetAsync(counts, 0, (size_t)N * sizeof(int), stream);
    hipMemsetAsync(pcount, 0, NPART * sizeof(int), stream);

    detect64_kernel<<<1, 64, 0, stream>>>(ei, E, N, flag);
    countA0_kernel<<<1024, 256, 0, stream>>>(ei, E, N, flag, pcount);
    setbase_kernel<<<1, 64, 0, stream>>>(pcount, pstart, pcur);
    passA_kernel<<<1024, 256, 0, stream>>>(ei, E, N, flag, pcur, srcbuf, dstbuf);
    // 1024 blocks co-resident (4/CU) so blockIdx%8 -> XCD pinning holds
    passB_hist_kernel<<<1024, 256, 0, stream>>>(dstbuf, pstart, pcount, counts);
    scanA_kernel<<<NB, 256, 0, stream>>>(counts, off, bsum, N);
    scanB_kernel<<<1, 64, 0, stream>>>(bsum, NB);
    scanC_kernel<<<(N + 255) / 256, 256, 0, stream>>>(off, bsum, N);
    dinv_kernel<<<(N + 255) / 256, 256, 0, stream>>>(counts, dinv, N);
    passC_scatter_kernel<<<1024, 256, 0, stream>>>(srcbuf, dstbuf, pstart, pcount,
                                                   off, csr_src);

    transform1_kernel<<<(N + 15) / 16, 256, 0, stream>>>(x, W1, dinv, g1, N);
    agg1_kernel<<<8192, 256, 0, stream>>>(off, csr_src, g1, dinv, b1, h, N);
    transform2_kernel<<<2048, 256, 0, stream>>>(h, W2, dinv, g2, N);
    agg2_kernel<<<8192, 256, 0, stream>>>(off, csr_src, g2, dinv, b2,
                                          (float*)d_out, N);
}

// Round 5
// 398.059 us; speedup vs baseline: 1.2423x; 1.2423x over previous
//
#include <hip/hip_runtime.h>
#include <math.h>

#define FIN 128
#define HID 16
#define NC 8
#define BSH 8                 // 256 nodes per bucket
#define BUKN 256              // nodes per bucket
#define MAXBUK 512            // supports N <= 131072
#define CH_PER_TH 16

// ---------------------------------------------------------------------------
// dtype probe: int64 vs int32 edge_index (device-side, uniform branch later)
// ---------------------------------------------------------------------------
__global__ void detect64_kernel(const void* __restrict__ ei, int E, int N,
                                int* __restrict__ flag) {
    if (blockIdx.x == 0 && threadIdx.x == 0) {
        const long long* p = (const long long*)ei;
        int ok = 1;
        for (int i = 0; i < 16; ++i) {
            long long v = p[i];
            if (v < 0 || v >= (long long)N) { ok = 0; break; }
        }
        *flag = ok;
    }
}

__device__ __forceinline__ int edge_at(const void* __restrict__ ei, long long pos, int is64) {
    return is64 ? (int)((const long long*)ei)[pos] : ((const int*)ei)[pos];
}

// A0: per-bucket edge counts. LDS hist; one line-padded global atomic per
// (block,bucket) -> ~100k atomics spread over nbuk distinct 64B lines.
__global__ void countA0_kernel(const void* __restrict__ ei, int E,
                               const int* __restrict__ flag,
                               int* __restrict__ pcount /*stride 16*/, int nbuk) {
    __shared__ int cnt[MAXBUK];
    const int is64 = *flag;
    const int t = threadIdx.x;
    for (int i = t; i < nbuk; i += 256) cnt[i] = 0;
    __syncthreads();
    for (long long e = (long long)blockIdx.x * blockDim.x + t; e < E;
         e += (long long)gridDim.x * blockDim.x) {
        int d = edge_at(ei, (long long)E + e, is64);
        atomicAdd(&cnt[d >> BSH], 1);
    }
    __syncthreads();
    for (int i = t; i < nbuk; i += 256)
        if (cnt[i]) atomicAdd(&pcount[i * 16], cnt[i]);
}

// exclusive scan of bucket counts -> pbase[nbuk+1], pcur (padded)
__global__ void setbase_kernel(const int* __restrict__ pcount,
                               int* __restrict__ pbase, int* __restrict__ pcur,
                               int nbuk) {
    if (blockIdx.x == 0 && threadIdx.x == 0) {
        int run = 0;
        for (int b = 0; b < nbuk; ++b) {
            pbase[b] = run; pcur[b * 16] = run; run += pcount[b * 16];
        }
        pbase[nbuk] = run;
    }
}

// A: counting-sort edges into dst-buckets (SoA src/dst). Per-(chunk,bucket)
// runs are contiguous & block-exclusive; in-chunk ordering via LDS cursors.
__global__ __launch_bounds__(256) void passA_kernel(
        const void* __restrict__ ei, int E, const int* __restrict__ flag,
        int* __restrict__ pcur, int* __restrict__ srcbuf, int* __restrict__ dstbuf,
        int nbuk) {
    const int is64 = *flag;
    __shared__ int cnt[MAXBUK], sbase[MAXBUK], lcur[MAXBUK];
    const int t = threadIdx.x;
    const int CH = 256 * CH_PER_TH;
    for (long long c0 = (long long)blockIdx.x * CH; c0 < E;
         c0 += (long long)gridDim.x * CH) {
        for (int i = t; i < nbuk; i += 256) cnt[i] = 0;
        __syncthreads();
        int sv[CH_PER_TH], dv[CH_PER_TH], bv[CH_PER_TH];
#pragma unroll
        for (int i = 0; i < CH_PER_TH; ++i) {
            long long e = c0 + t + i * 256;
            bv[i] = -1;
            if (e < E) {
                int s = edge_at(ei, e, is64);
                int d = edge_at(ei, (long long)E + e, is64);
                sv[i] = s; dv[i] = d; bv[i] = d >> BSH;
                atomicAdd(&cnt[bv[i]], 1);
            }
        }
        __syncthreads();
        for (int i = t; i < nbuk; i += 256) {
            sbase[i] = cnt[i] ? atomicAdd(&pcur[i * 16], cnt[i]) : 0;
            lcur[i] = 0;
        }
        __syncthreads();
#pragma unroll
        for (int i = 0; i < CH_PER_TH; ++i) {
            if (bv[i] >= 0) {
                int pos = sbase[bv[i]] + atomicAdd(&lcur[bv[i]], 1);
                srcbuf[pos] = sv[i];
                dstbuf[pos] = dv[i];
            }
        }
        __syncthreads();
    }
}

// B: one block per bucket; LDS histogram of the bucket's 256 nodes; plain
// coalesced write to counts (fully written -> no memset needed).
__global__ void passB_hist_kernel(const int* __restrict__ dstbuf,
                                  const int* __restrict__ pbase,
                                  int* __restrict__ counts, int N) {
    __shared__ int c[BUKN];
    const int b = blockIdx.x;
    const int t = threadIdx.x;
    c[t] = 0;
    __syncthreads();
    const int ebeg = pbase[b], eend = pbase[b + 1];
    for (int i = ebeg + t; i < eend; i += 256)
        atomicAdd(&c[dstbuf[i] & (BUKN - 1)], 1);
    __syncthreads();
    int n = (b << BSH) + t;
    if (n < N) counts[n] = c[t];
}

// exclusive scan, stage A: 1024 elements/block (256 thr x 4), block totals out
__global__ void scanA_kernel(const int* __restrict__ counts, int* __restrict__ off,
                             int* __restrict__ bsum, int N) {
    __shared__ int s[256];
    int b = blockIdx.x, t = threadIdx.x;
    int base = b * 1024 + t * 4;
    int v[4], tot = 0;
#pragma unroll
    for (int i = 0; i < 4; ++i) {
        int idx = base + i;
        v[i] = (idx < N) ? counts[idx] : 0;
        tot += v[i];
    }
    s[t] = tot;
    __syncthreads();
    for (int d = 1; d < 256; d <<= 1) {
        int add = (t >= d) ? s[t - d] : 0;
        __syncthreads();
        s[t] += add;
        __syncthreads();
    }
    if (t == 255) bsum[b] = s[255];
    int run = (t > 0) ? s[t - 1] : 0;
#pragma unroll
    for (int i = 0; i < 4; ++i) {
        int idx = base + i;
        if (idx < N) off[idx] = run;
        run += v[i];
    }
}

__global__ void scanB_kernel(int* __restrict__ bsum, int nb) {
    if (threadIdx.x == 0 && blockIdx.x == 0) {
        int run = 0;
        for (int i = 0; i < nb; ++i) { int v = bsum[i]; bsum[i] = run; run += v; }
    }
}

__global__ void scanC_kernel(int* __restrict__ off, const int* __restrict__ bsum, int N) {
    int i = blockIdx.x * blockDim.x + threadIdx.x;
    if (i < N) off[i] += bsum[i >> 10];
}

// dinv[n] = rsqrt(counts[n] + 1)   (self loop adds 1)
__global__ void dinv_kernel(const int* __restrict__ counts, float* __restrict__ dinv, int N) {
    int n = blockIdx.x * blockDim.x + threadIdx.x;
    if (n < N) dinv[n] = rsqrtf((float)(counts[n] + 1));
}

// C: one block per bucket; LDS cursors (init from off = exclusive start);
// per-edge LDS atomic; csr writes land in the bucket's contiguous ~32KB
// slice -> L2-resident, evicts once. Writeback makes off[n] = inclusive end.
__global__ void passC_scatter_kernel(const int* __restrict__ srcbuf,
                                     const int* __restrict__ dstbuf,
                                     const int* __restrict__ pbase,
                                     int* __restrict__ off, int* __restrict__ csr_src,
                                     int N) {
    __shared__ int cur[BUKN];
    const int b = blockIdx.x;
    const int t = threadIdx.x;
    const int n0 = (b << BSH) + t;
    cur[t] = (n0 < N) ? off[n0] : 0;
    __syncthreads();
    const int ebeg = pbase[b], eend = pbase[b + 1];
    for (int i = ebeg + t; i < eend; i += 256) {
        int d = dstbuf[i];
        int pos = atomicAdd(&cur[d & (BUKN - 1)], 1);
        csr_src[pos] = srcbuf[i];
    }
    __syncthreads();
    if (n0 < N) off[n0] = cur[t];
}

// g1[n][k] = (sum_f x[n][f] * W1[f][k]) * dinv[n]
__global__ void transform1_kernel(const float* __restrict__ x,
                                  const float* __restrict__ W1,
                                  const float* __restrict__ dinv,
                                  float* __restrict__ g1, int N) {
    __shared__ float xs[16][FIN + 4];
    __shared__ float w[FIN][HID];
    const int t = threadIdx.x;
    for (int i = t; i < FIN * HID; i += 256) w[i / HID][i % HID] = W1[i];

    const float4* x4 = (const float4*)x;
    for (int rb = blockIdx.x * 16; rb < N; rb += gridDim.x * 16) {
        __syncthreads();
        for (int i = t; i < 16 * FIN / 4; i += 256) {
            int r = i >> 5, f4 = i & 31;
            int row = rb + r;
            float4 v = (row < N) ? x4[(size_t)row * (FIN / 4) + f4]
                                 : make_float4(0.f, 0.f, 0.f, 0.f);
            *((float4*)&xs[r][f4 * 4]) = v;
        }
        __syncthreads();
        int r = t >> 4, k = t & 15;
        int row = rb + r;
        if (row < N) {
            float s = 0.f;
#pragma unroll
            for (int f = 0; f < FIN; ++f) s += xs[r][f] * w[f][k];
            g1[(size_t)row * HID + k] = s * dinv[row];
        }
    }
}

// wave per node: 16 feature lanes x 4 edge-ways; fused ReLU finalize
__global__ void agg1_kernel(const int* __restrict__ off, const int* __restrict__ csr_src,
                            const float* __restrict__ g1, const float* __restrict__ dinv,
                            const float* __restrict__ b1, float* __restrict__ h, int N) {
    int wid = threadIdx.x >> 6;
    int lane = threadIdx.x & 63;
    int k = lane & 15, j = lane >> 4;                 // j in 0..3
    int wavesTotal = gridDim.x * (blockDim.x >> 6);
    for (int n = blockIdx.x * (blockDim.x >> 6) + wid; n < N; n += wavesTotal) {
        int start = (n == 0) ? 0 : off[n - 1];        // off[] holds END after scatter
        int end = off[n];
        float sum = 0.f;
        for (int e = start + j; e < end; e += 4)
            sum += g1[(size_t)csr_src[e] * HID + k];
        sum += __shfl_xor(sum, 16, 64);
        sum += __shfl_xor(sum, 32, 64);
        if (lane < 16) {
            float v = dinv[n] * (sum + g1[(size_t)n * HID + k]) + b1[k];
            h[(size_t)n * HID + k] = fmaxf(v, 0.f);
        }
    }
}

// g2[n][c] = (sum_k h[n][k] * W2[k][c]) * dinv[n]
__global__ void transform2_kernel(const float* __restrict__ h,
                                  const float* __restrict__ W2,
                                  const float* __restrict__ dinv,
                                  float* __restrict__ g2, int N) {
    int total = N * NC;
    for (int idx = blockIdx.x * blockDim.x + threadIdx.x; idx < total;
         idx += gridDim.x * blockDim.x) {
        int n = idx >> 3, c = idx & 7;
        float s = 0.f;
#pragma unroll
        for (int k = 0; k < HID; ++k) s += h[n * HID + k] * W2[k * NC + c];
        g2[idx] = s * dinv[n];
    }
}

// wave per node: 8 feature lanes x 8 edge-ways; fused log_softmax
__global__ void agg2_kernel(const int* __restrict__ off, const int* __restrict__ csr_src,
                            const float* __restrict__ g2, const float* __restrict__ dinv,
                            const float* __restrict__ b2, float* __restrict__ out, int N) {
    int wid = threadIdx.x >> 6;
    int lane = threadIdx.x & 63;
    int k = lane & 7, j = lane >> 3;                  // j in 0..7
    int wavesTotal = gridDim.x * (blockDim.x >> 6);
    for (int n = blockIdx.x * (blockDim.x >> 6) + wid; n < N; n += wavesTotal) {
        int start = (n == 0) ? 0 : off[n - 1];
        int end = off[n];
        float sum = 0.f;
        for (int e = start + j; e < end; e += 8)
            sum += g2[(size_t)csr_src[e] * NC + k];
        sum += __shfl_xor(sum, 8, 64);
        sum += __shfl_xor(sum, 16, 64);
        sum += __shfl_xor(sum, 32, 64);
        float logit = dinv[n] * (sum + g2[(size_t)n * NC + k]) + b2[k];
        float m = logit;
        m = fmaxf(m, __shfl_xor(m, 1, 64));
        m = fmaxf(m, __shfl_xor(m, 2, 64));
        m = fmaxf(m, __shfl_xor(m, 4, 64));
        float ex = __expf(logit - m);
        float s = ex;
        s += __shfl_xor(s, 1, 64);
        s += __shfl_xor(s, 2, 64);
        s += __shfl_xor(s, 4, 64);
        float lse = m + __logf(s);
        if (lane < 8) out[(size_t)n * NC + k] = logit - lse;
    }
}

extern "C" void kernel_launch(void* const* d_in, const int* in_sizes, int n_in,
                              void* d_out, int out_size, void* d_ws, size_t ws_size,
                              hipStream_t stream) {
    const float* x  = (const float*)d_in[0];
    const void*  ei = d_in[1];
    const float* W1 = (const float*)d_in[2];
    const float* b1 = (const float*)d_in[3];
    const float* W2 = (const float*)d_in[4];
    const float* b2 = (const float*)d_in[5];

    const int N = in_sizes[0] / FIN;
    const int E = in_sizes[1] / 2;
    const int NB = (N + 1023) / 1024;
    const int nbuk = (N + BUKN - 1) >> BSH;          // 391 for N=100k (<= MAXBUK)

    char* p = (char*)d_ws;
    int*   counts  = (int*)p;            p += (size_t)N * 4;
    int*   off     = (int*)p;            p += (size_t)N * 4;
    int*   bsum    = (int*)p;            p += (size_t)((NB + 63) & ~63) * 4;
    int*   csr_src = (int*)p;            p += (size_t)E * 4;
    float* dinv    = (float*)p;          p += (size_t)N * 4;
    int*   srcbuf  = (int*)p;            p += (size_t)E * 4;   // reused: g1
    int*   dstbuf  = (int*)p;            p += (size_t)E * 4;   // reused: h, g2
    int*   pcount  = (int*)p;            p += (size_t)MAXBUK * 16 * 4;  // line-padded
    int*   pcur    = (int*)p;            p += (size_t)MAXBUK * 16 * 4;  // line-padded
    int*   pbase   = (int*)p;            p += (size_t)(MAXBUK + 1) * 4;
    int*   flag    = (int*)p;

    // aliases (consumed edge buffers reused as activation storage)
    float* g1 = (float*)srcbuf;                    // N*HID <= E floats
    float* h  = (float*)dstbuf;                    // N*HID
    float* g2 = (float*)dstbuf + (size_t)N * HID;  // N*NC

    hipMemsetAsync(pcount, 0, (size_t)MAXBUK * 16 * 4, stream);

    detect64_kernel<<<1, 64, 0, stream>>>(ei, E, N, flag);
    countA0_kernel<<<256, 256, 0, stream>>>(ei, E, flag, pcount, nbuk);
    setbase_kernel<<<1, 64, 0, stream>>>(pcount, pbase, pcur, nbuk);
    passA_kernel<<<(E + 4095) / 4096, 256, 0, stream>>>(ei, E, flag, pcur,
                                                        srcbuf, dstbuf, nbuk);
    passB_hist_kernel<<<nbuk, 256, 0, stream>>>(dstbuf, pbase, counts, N);
    scanA_kernel<<<NB, 256, 0, stream>>>(counts, off, bsum, N);
    scanB_kernel<<<1, 64, 0, stream>>>(bsum, NB);
    scanC_kernel<<<(N + 255) / 256, 256, 0, stream>>>(off, bsum, N);
    dinv_kernel<<<(N + 255) / 256, 256, 0, stream>>>(counts, dinv, N);
    passC_scatter_kernel<<<nbuk, 256, 0, stream>>>(srcbuf, dstbuf, pbase,
                                                   off, csr_src, N);

    transform1_kernel<<<(N + 15) / 16, 256, 0, stream>>>(x, W1, dinv, g1, N);
    agg1_kernel<<<8192, 256, 0, stream>>>(off, csr_src, g1, dinv, b1, h, N);
    transform2_kernel<<<2048, 256, 0, stream>>>(h, W2, dinv, g2, N);
    agg2_kernel<<<8192, 256, 0, stream>>>(off, csr_src, g2, dinv, b2,
                                          (float*)d_out, N);
}

// Round 6
// 304.268 us; speedup vs baseline: 1.6253x; 1.3083x over previous
//
#include <hip/hip_runtime.h>
#include <math.h>

#define FIN 128
#define HID 16
#define NC 8
#define BSH 8                 // 256 nodes per bucket
#define BUKN 256              // nodes per bucket
#define MAXBUK 512            // supports N <= 131072
#define CH_PER_TH 16

// ---------------------------------------------------------------------------
// dtype probe: int64 vs int32 edge_index (device-side, uniform branch later)
// ---------------------------------------------------------------------------
__global__ void detect64_kernel(const void* __restrict__ ei, int E, int N,
                                int* __restrict__ flag) {
    if (blockIdx.x == 0 && threadIdx.x == 0) {
        const long long* p = (const long long*)ei;
        int ok = 1;
        for (int i = 0; i < 16; ++i) {
            long long v = p[i];
            if (v < 0 || v >= (long long)N) { ok = 0; break; }
        }
        *flag = ok;
    }
}

__device__ __forceinline__ int edge_at(const void* __restrict__ ei, long long pos, int is64) {
    return is64 ? (int)((const long long*)ei)[pos] : ((const int*)ei)[pos];
}

// A0: per-bucket edge counts. LDS hist; one line-padded global atomic per
// (block,bucket) -> ~100k atomics spread over nbuk distinct 64B lines.
__global__ void countA0_kernel(const void* __restrict__ ei, int E,
                               const int* __restrict__ flag,
                               int* __restrict__ pcount /*stride 16*/, int nbuk) {
    __shared__ int cnt[MAXBUK];
    const int is64 = *flag;
    const int t = threadIdx.x;
    for (int i = t; i < nbuk; i += 256) cnt[i] = 0;
    __syncthreads();
    for (long long e = (long long)blockIdx.x * blockDim.x + t; e < E;
         e += (long long)gridDim.x * blockDim.x) {
        int d = edge_at(ei, (long long)E + e, is64);
        atomicAdd(&cnt[d >> BSH], 1);
    }
    __syncthreads();
    for (int i = t; i < nbuk; i += 256)
        if (cnt[i]) atomicAdd(&pcount[i * 16], cnt[i]);
}

// parallel exclusive scan of bucket counts -> pbase[nbuk+1], pcur (padded).
// one block, 256 threads, 2 elements each (nbuk <= MAXBUK = 512).
__global__ void setbase_kernel(const int* __restrict__ pcount,
                               int* __restrict__ pbase, int* __restrict__ pcur,
                               int nbuk) {
    __shared__ int s[256];
    const int t = threadIdx.x;
    int i0 = 2 * t, i1 = 2 * t + 1;
    int v0 = (i0 < nbuk) ? pcount[i0 * 16] : 0;
    int v1 = (i1 < nbuk) ? pcount[i1 * 16] : 0;
    s[t] = v0 + v1;
    __syncthreads();
    for (int d = 1; d < 256; d <<= 1) {
        int add = (t >= d) ? s[t - d] : 0;
        __syncthreads();
        s[t] += add;
        __syncthreads();
    }
    int base = (t > 0) ? s[t - 1] : 0;     // exclusive pair-base
    if (i0 < nbuk) { pbase[i0] = base; pcur[i0 * 16] = base; }
    if (i1 < nbuk) { pbase[i1] = base + v0; pcur[i1 * 16] = base + v0; }
    if (t == 255) pbase[nbuk] = s[255];
}

// A: counting-sort edges into dst-buckets (SoA src/dst). Per-(chunk,bucket)
// runs are contiguous & block-exclusive; in-chunk ordering via LDS cursors.
__global__ __launch_bounds__(256) void passA_kernel(
        const void* __restrict__ ei, int E, const int* __restrict__ flag,
        int* __restrict__ pcur, int* __restrict__ srcbuf, int* __restrict__ dstbuf,
        int nbuk) {
    const int is64 = *flag;
    __shared__ int cnt[MAXBUK], sbase[MAXBUK], lcur[MAXBUK];
    const int t = threadIdx.x;
    const int CH = 256 * CH_PER_TH;
    for (long long c0 = (long long)blockIdx.x * CH; c0 < E;
         c0 += (long long)gridDim.x * CH) {
        for (int i = t; i < nbuk; i += 256) cnt[i] = 0;
        __syncthreads();
        int sv[CH_PER_TH], dv[CH_PER_TH], bv[CH_PER_TH];
#pragma unroll
        for (int i = 0; i < CH_PER_TH; ++i) {
            long long e = c0 + t + i * 256;
            bv[i] = -1;
            if (e < E) {
                int s = edge_at(ei, e, is64);
                int d = edge_at(ei, (long long)E + e, is64);
                sv[i] = s; dv[i] = d; bv[i] = d >> BSH;
                atomicAdd(&cnt[bv[i]], 1);
            }
        }
        __syncthreads();
        for (int i = t; i < nbuk; i += 256) {
            sbase[i] = cnt[i] ? atomicAdd(&pcur[i * 16], cnt[i]) : 0;
            lcur[i] = 0;
        }
        __syncthreads();
#pragma unroll
        for (int i = 0; i < CH_PER_TH; ++i) {
            if (bv[i] >= 0) {
                int pos = sbase[bv[i]] + atomicAdd(&lcur[bv[i]], 1);
                srcbuf[pos] = sv[i];
                dstbuf[pos] = dv[i];
            }
        }
        __syncthreads();
    }
}

// B: one block per bucket; LDS histogram of the bucket's 256 nodes; plain
// coalesced write to counts (fully written -> no memset needed).
__global__ void passB_hist_kernel(const int* __restrict__ dstbuf,
                                  const int* __restrict__ pbase,
                                  int* __restrict__ counts, int N) {
    __shared__ int c[BUKN];
    const int b = blockIdx.x;
    const int t = threadIdx.x;
    c[t] = 0;
    __syncthreads();
    const int ebeg = pbase[b], eend = pbase[b + 1];
    for (int i = ebeg + t; i < eend; i += 256)
        atomicAdd(&c[dstbuf[i] & (BUKN - 1)], 1);
    __syncthreads();
    int n = (b << BSH) + t;
    if (n < N) counts[n] = c[t];
}

// exclusive scan, stage A: 1024 elements/block (256 thr x 4), block totals out
__global__ void scanA_kernel(const int* __restrict__ counts, int* __restrict__ off,
                             int* __restrict__ bsum, int N) {
    __shared__ int s[256];
    int b = blockIdx.x, t = threadIdx.x;
    int base = b * 1024 + t * 4;
    int v[4], tot = 0;
#pragma unroll
    for (int i = 0; i < 4; ++i) {
        int idx = base + i;
        v[i] = (idx < N) ? counts[idx] : 0;
        tot += v[i];
    }
    s[t] = tot;
    __syncthreads();
    for (int d = 1; d < 256; d <<= 1) {
        int add = (t >= d) ? s[t - d] : 0;
        __syncthreads();
        s[t] += add;
        __syncthreads();
    }
    if (t == 255) bsum[b] = s[255];
    int run = (t > 0) ? s[t - 1] : 0;
#pragma unroll
    for (int i = 0; i < 4; ++i) {
        int idx = base + i;
        if (idx < N) off[idx] = run;
        run += v[i];
    }
}

// parallel exclusive scan of block sums (nb <= 256), one block
__global__ void scanB_kernel(int* __restrict__ bsum, int nb) {
    __shared__ int s[256];
    const int t = threadIdx.x;
    int v = (t < nb) ? bsum[t] : 0;
    s[t] = v;
    __syncthreads();
    for (int d = 1; d < 256; d <<= 1) {
        int add = (t >= d) ? s[t - d] : 0;
        __syncthreads();
        s[t] += add;
        __syncthreads();
    }
    if (t < nb) bsum[t] = s[t] - v;        // exclusive
}

__global__ void scanC_kernel(int* __restrict__ off, const int* __restrict__ bsum, int N) {
    int i = blockIdx.x * blockDim.x + threadIdx.x;
    if (i < N) off[i] += bsum[i >> 10];
}

// dinv[n] = rsqrt(counts[n] + 1)   (self loop adds 1)
__global__ void dinv_kernel(const int* __restrict__ counts, float* __restrict__ dinv, int N) {
    int n = blockIdx.x * blockDim.x + threadIdx.x;
    if (n < N) dinv[n] = rsqrtf((float)(counts[n] + 1));
}

// C: one block per bucket; LDS cursors (init from off = exclusive start);
// per-edge LDS atomic; csr writes land in the bucket's contiguous ~32KB
// slice -> L2-resident, evicts once. Writeback makes off[n] = inclusive end.
__global__ void passC_scatter_kernel(const int* __restrict__ srcbuf,
                                     const int* __restrict__ dstbuf,
                                     const int* __restrict__ pbase,
                                     int* __restrict__ off, int* __restrict__ csr_src,
                                     int N) {
    __shared__ int cur[BUKN];
    const int b = blockIdx.x;
    const int t = threadIdx.x;
    const int n0 = (b << BSH) + t;
    cur[t] = (n0 < N) ? off[n0] : 0;
    __syncthreads();
    const int ebeg = pbase[b], eend = pbase[b + 1];
    for (int i = ebeg + t; i < eend; i += 256) {
        int d = dstbuf[i];
        int pos = atomicAdd(&cur[d & (BUKN - 1)], 1);
        csr_src[pos] = srcbuf[i];
    }
    __syncthreads();
    if (n0 < N) off[n0] = cur[t];
}

// g1[n][k] = (sum_f x[n][f] * W1[f][k]) * dinv[n]
__global__ void transform1_kernel(const float* __restrict__ x,
                                  const float* __restrict__ W1,
                                  const float* __restrict__ dinv,
                                  float* __restrict__ g1, int N) {
    __shared__ float xs[16][FIN + 4];
    __shared__ float w[FIN][HID];
    const int t = threadIdx.x;
    for (int i = t; i < FIN * HID; i += 256) w[i / HID][i % HID] = W1[i];

    const float4* x4 = (const float4*)x;
    for (int rb = blockIdx.x * 16; rb < N; rb += gridDim.x * 16) {
        __syncthreads();
        for (int i = t; i < 16 * FIN / 4; i += 256) {
            int r = i >> 5, f4 = i & 31;
            int row = rb + r;
            float4 v = (row < N) ? x4[(size_t)row * (FIN / 4) + f4]
                                 : make_float4(0.f, 0.f, 0.f, 0.f);
            *((float4*)&xs[r][f4 * 4]) = v;
        }
        __syncthreads();
        int r = t >> 4, k = t & 15;
        int row = rb + r;
        if (row < N) {
            float s = 0.f;
#pragma unroll
            for (int f = 0; f < FIN; ++f) s += xs[r][f] * w[f][k];
            g1[(size_t)row * HID + k] = s * dinv[row];
        }
    }
}

// wave per node: 16 feature lanes x 4 edge-ways; fused ReLU finalize
__global__ void agg1_kernel(const int* __restrict__ off, const int* __restrict__ csr_src,
                            const float* __restrict__ g1, const float* __restrict__ dinv,
                            const float* __restrict__ b1, float* __restrict__ h, int N) {
    int wid = threadIdx.x >> 6;
    int lane = threadIdx.x & 63;
    int k = lane & 15, j = lane >> 4;                 // j in 0..3
    int wavesTotal = gridDim.x * (blockDim.x >> 6);
    for (int n = blockIdx.x * (blockDim.x >> 6) + wid; n < N; n += wavesTotal) {
        int start = (n == 0) ? 0 : off[n - 1];        // off[] holds END after scatter
        int end = off[n];
        float sum = 0.f;
        for (int e = start + j; e < end; e += 4)
            sum += g1[(size_t)csr_src[e] * HID + k];
        sum += __shfl_xor(sum, 16, 64);
        sum += __shfl_xor(sum, 32, 64);
        if (lane < 16) {
            float v = dinv[n] * (sum + g1[(size_t)n * HID + k]) + b1[k];
            h[(size_t)n * HID + k] = fmaxf(v, 0.f);
        }
    }
}

// g2[n][c] = (sum_k h[n][k] * W2[k][c]) * dinv[n]
__global__ void transform2_kernel(const float* __restrict__ h,
                                  const float* __restrict__ W2,
                                  const float* __restrict__ dinv,
                                  float* __restrict__ g2, int N) {
    int total = N * NC;
    for (int idx = blockIdx.x * blockDim.x + threadIdx.x; idx < total;
         idx += gridDim.x * blockDim.x) {
        int n = idx >> 3, c = idx & 7;
        float s = 0.f;
#pragma unroll
        for (int k = 0; k < HID; ++k) s += h[n * HID + k] * W2[k * NC + c];
        g2[idx] = s * dinv[n];
    }
}

// wave per node: 8 feature lanes x 8 edge-ways; fused log_softmax
__global__ void agg2_kernel(const int* __restrict__ off, const int* __restrict__ csr_src,
                            const float* __restrict__ g2, const float* __restrict__ dinv,
                            const float* __restrict__ b2, float* __restrict__ out, int N) {
    int wid = threadIdx.x >> 6;
    int lane = threadIdx.x & 63;
    int k = lane & 7, j = lane >> 3;                  // j in 0..7
    int wavesTotal = gridDim.x * (blockDim.x >> 6);
    for (int n = blockIdx.x * (blockDim.x >> 6) + wid; n < N; n += wavesTotal) {
        int start = (n == 0) ? 0 : off[n - 1];
        int end = off[n];
        float sum = 0.f;
        for (int e = start + j; e < end; e += 8)
            sum += g2[(size_t)csr_src[e] * NC + k];
        sum += __shfl_xor(sum, 8, 64);
        sum += __shfl_xor(sum, 16, 64);
        sum += __shfl_xor(sum, 32, 64);
        float logit = dinv[n] * (sum + g2[(size_t)n * NC + k]) + b2[k];
        float m = logit;
        m = fmaxf(m, __shfl_xor(m, 1, 64));
        m = fmaxf(m, __shfl_xor(m, 2, 64));
        m = fmaxf(m, __shfl_xor(m, 4, 64));
        float ex = __expf(logit - m);
        float s = ex;
        s += __shfl_xor(s, 1, 64);
        s += __shfl_xor(s, 2, 64);
        s += __shfl_xor(s, 4, 64);
        float lse = m + __logf(s);
        if (lane < 8) out[(size_t)n * NC + k] = logit - lse;
    }
}

extern "C" void kernel_launch(void* const* d_in, const int* in_sizes, int n_in,
                              void* d_out, int out_size, void* d_ws, size_t ws_size,
                              hipStream_t stream) {
    const float* x  = (const float*)d_in[0];
    const void*  ei = d_in[1];
    const float* W1 = (const float*)d_in[2];
    const float* b1 = (const float*)d_in[3];
    const float* W2 = (const float*)d_in[4];
    const float* b2 = (const float*)d_in[5];

    const int N = in_sizes[0] / FIN;
    const int E = in_sizes[1] / 2;
    const int NB = (N + 1023) / 1024;
    const int nbuk = (N + BUKN - 1) >> BSH;          // 391 for N=100k (<= MAXBUK)

    char* p = (char*)d_ws;
    int*   counts  = (int*)p;            p += (size_t)N * 4;
    int*   off     = (int*)p;            p += (size_t)N * 4;
    int*   bsum    = (int*)p;            p += (size_t)((NB + 63) & ~63) * 4;
    int*   csr_src = (int*)p;            p += (size_t)E * 4;
    float* dinv    = (float*)p;          p += (size_t)N * 4;
    int*   srcbuf  = (int*)p;            p += (size_t)E * 4;   // reused: g1
    int*   dstbuf  = (int*)p;            p += (size_t)E * 4;   // reused: h, g2
    int*   pcount  = (int*)p;            p += (size_t)MAXBUK * 16 * 4;  // line-padded
    int*   pcur    = (int*)p;            p += (size_t)MAXBUK * 16 * 4;  // line-padded
    int*   pbase   = (int*)p;            p += (size_t)(MAXBUK + 1) * 4;
    int*   flag    = (int*)p;

    // aliases (consumed edge buffers reused as activation storage)
    float* g1 = (float*)srcbuf;                    // N*HID <= E floats
    float* h  = (float*)dstbuf;                    // N*HID
    float* g2 = (float*)dstbuf + (size_t)N * HID;  // N*NC

    hipMemsetAsync(pcount, 0, (size_t)MAXBUK * 16 * 4, stream);

    detect64_kernel<<<1, 64, 0, stream>>>(ei, E, N, flag);
    countA0_kernel<<<256, 256, 0, stream>>>(ei, E, flag, pcount, nbuk);
    setbase_kernel<<<1, 256, 0, stream>>>(pcount, pbase, pcur, nbuk);
    passA_kernel<<<(E + 4095) / 4096, 256, 0, stream>>>(ei, E, flag, pcur,
                                                        srcbuf, dstbuf, nbuk);
    passB_hist_kernel<<<nbuk, 256, 0, stream>>>(dstbuf, pbase, counts, N);
    scanA_kernel<<<NB, 256, 0, stream>>>(counts, off, bsum, N);
    scanB_kernel<<<1, 256, 0, stream>>>(bsum, NB);
    scanC_kernel<<<(N + 255) / 256, 256, 0, stream>>>(off, bsum, N);
    dinv_kernel<<<(N + 255) / 256, 256, 0, stream>>>(counts, dinv, N);
    passC_scatter_kernel<<<nbuk, 256, 0, stream>>>(srcbuf, dstbuf, pbase,
                                                   off, csr_src, N);

    transform1_kernel<<<(N + 15) / 16, 256, 0, stream>>>(x, W1, dinv, g1, N);
    agg1_kernel<<<8192, 256, 0, stream>>>(off, csr_src, g1, dinv, b1, h, N);
    transform2_kernel<<<2048, 256, 0, stream>>>(h, W2, dinv, g2, N);
    agg2_kernel<<<8192, 256, 0, stream>>>(off, csr_src, g2, dinv, b2,
                                          (float*)d_out, N);
}